// Round 1
// baseline (6117.970 us; speedup 1.0000x reference)
//
#include <hip/hip_runtime.h>
#include <math.h>

#define NEG_SLOPE 0.2f

__device__ __forceinline__ float leaky(float x) { return x > 0.f ? x : NEG_SLOPE * x; }
// monotonic float->uint encoding for atomicMax on floats
__device__ __forceinline__ unsigned enc(float f) {
    unsigned u = __float_as_uint(f);
    return (u & 0x80000000u) ? ~u : (u | 0x80000000u);
}
__device__ __forceinline__ float dec(unsigned e) {
    return (e & 0x80000000u) ? __uint_as_float(e ^ 0x80000000u) : __uint_as_float(~e);
}

// ---------------- GEMM: C[M,Nc] = A[M,K] @ B[K,Nc]; Nc %64==0, K %32==0 -------------
__global__ __launch_bounds__(256) void gemm_tile(const float* __restrict__ A,
                                                 const float* __restrict__ B,
                                                 float* __restrict__ C,
                                                 int M, int Nc, int K) {
    __shared__ float As[32][64];  // [k][m]
    __shared__ float Bs[32][64];  // [k][n]
    const int tid = threadIdx.x;
    const int m0 = blockIdx.x * 64;
    const int n0 = blockIdx.y * 64;
    const int tx = tid & 15, ty = tid >> 4;
    float acc[4][4] = {};
    for (int k0 = 0; k0 < K; k0 += 32) {
        {   // A tile 64 rows x 32 cols, store transposed
            int r = tid >> 3, c4 = tid & 7;
#pragma unroll
            for (int l = 0; l < 2; ++l) {
                int row = r + l * 32;
                float4 v = make_float4(0.f, 0.f, 0.f, 0.f);
                if (m0 + row < M) v = *(const float4*)&A[(size_t)(m0 + row) * K + k0 + c4 * 4];
                As[c4 * 4 + 0][row] = v.x;
                As[c4 * 4 + 1][row] = v.y;
                As[c4 * 4 + 2][row] = v.z;
                As[c4 * 4 + 3][row] = v.w;
            }
        }
        {   // B tile 32 rows x 64 cols
            int kr = tid >> 4, c4 = tid & 15;
#pragma unroll
            for (int l = 0; l < 2; ++l) {
                int row = kr + l * 16;
                float4 v = *(const float4*)&B[(size_t)(k0 + row) * Nc + n0 + c4 * 4];
                *(float4*)&Bs[row][c4 * 4] = v;
            }
        }
        __syncthreads();
#pragma unroll
        for (int k = 0; k < 32; ++k) {
            float a0 = As[k][ty * 4 + 0], a1 = As[k][ty * 4 + 1];
            float a2 = As[k][ty * 4 + 2], a3 = As[k][ty * 4 + 3];
            float4 b = *(const float4*)&Bs[k][tx * 4];
            acc[0][0] += a0 * b.x; acc[0][1] += a0 * b.y; acc[0][2] += a0 * b.z; acc[0][3] += a0 * b.w;
            acc[1][0] += a1 * b.x; acc[1][1] += a1 * b.y; acc[1][2] += a1 * b.z; acc[1][3] += a1 * b.w;
            acc[2][0] += a2 * b.x; acc[2][1] += a2 * b.y; acc[2][2] += a2 * b.z; acc[2][3] += a2 * b.w;
            acc[3][0] += a3 * b.x; acc[3][1] += a3 * b.y; acc[3][2] += a3 * b.z; acc[3][3] += a3 * b.w;
        }
        __syncthreads();
    }
#pragma unroll
    for (int i = 0; i < 4; ++i) {
        int row = m0 + ty * 4 + i;
        if (row < M) {
            float4 v = make_float4(acc[i][0], acc[i][1], acc[i][2], acc[i][3]);
            *(float4*)&C[(size_t)row * Nc + n0 + tx * 4] = v;
        }
    }
}

// ------------- layer0 el/er: [N,4] each, plus global max (encoded) -------------
__global__ __launch_bounds__(256) void elr0_kernel(const float* __restrict__ feat,
                                                   const float* __restrict__ al,
                                                   const float* __restrict__ ar,
                                                   float* __restrict__ el, float* __restrict__ er,
                                                   unsigned* __restrict__ gmax) {
    int n = blockIdx.x, tid = threadIdx.x;
    float v = feat[(size_t)n * 256 + tid];
    float pe = v * al[tid];
    float pr = v * ar[tid];
#pragma unroll
    for (int o = 32; o > 0; o >>= 1) {
        pe += __shfl_xor(pe, o);
        pr += __shfl_xor(pr, o);
    }
    int lane = tid & 63, h = tid >> 6;  // wave == head
    if (lane == 0) {
        el[n * 4 + h] = pe;
        er[n * 4 + h] = pr;
        atomicMax(&gmax[h], enc(pe));
        atomicMax(&gmax[4 + h], enc(pr));
    }
}

// ------------- layer1 el/er: [N] each ------------------------------------------
__global__ __launch_bounds__(64) void elr1_kernel(const float* __restrict__ fcat,
                                                  const float* __restrict__ al,
                                                  const float* __restrict__ ar,
                                                  float* __restrict__ el, float* __restrict__ er,
                                                  unsigned* __restrict__ gmax) {
    int n = blockIdx.x, lane = threadIdx.x;
    float pe = 0.f, pr = 0.f;
    if (lane < 32) {
        float v = fcat[(size_t)n * 64 + lane];
        pe = v * al[lane];
        pr = v * ar[lane];
    }
#pragma unroll
    for (int o = 16; o > 0; o >>= 1) {
        pe += __shfl_xor(pe, o);
        pr += __shfl_xor(pr, o);
    }
    if (lane == 0) {
        el[n] = pe;
        er[n] = pr;
        atomicMax(&gmax[8], enc(pe));
        atomicMax(&gmax[9], enc(pr));
    }
}

// ------------- CSR build ---------------------------------------------------------
__global__ void count_kernel(const int* __restrict__ dst, int* __restrict__ deg, int E) {
    int e = blockIdx.x * 256 + threadIdx.x;
    if (e < E) atomicAdd(&deg[dst[e]], 1);
}

__global__ __launch_bounds__(256) void scanA(const int* __restrict__ deg, int* __restrict__ bsum, int N) {
    int i = blockIdx.x * 256 + threadIdx.x;
    int v = (i < N) ? deg[i] : 0;
#pragma unroll
    for (int o = 32; o > 0; o >>= 1) v += __shfl_xor(v, o);
    __shared__ int s[4];
    if ((threadIdx.x & 63) == 0) s[threadIdx.x >> 6] = v;
    __syncthreads();
    if (threadIdx.x == 0) bsum[blockIdx.x] = s[0] + s[1] + s[2] + s[3];
}

__global__ __launch_bounds__(256) void scanB(const int* __restrict__ bsum, int* __restrict__ bpre, int nb) {
    __shared__ int s[256];
    int t = threadIdx.x;
    int v = (t < nb) ? bsum[t] : 0;
    s[t] = v;
    __syncthreads();
    for (int o = 1; o < 256; o <<= 1) {
        int x = (t >= o) ? s[t - o] : 0;
        __syncthreads();
        s[t] += x;
        __syncthreads();
    }
    if (t < nb) bpre[t] = s[t] - v;  // exclusive
}

__global__ __launch_bounds__(256) void scanC(const int* __restrict__ deg, const int* __restrict__ bpre,
                                             int* __restrict__ off, int N) {
    int b = blockIdx.x, t = threadIdx.x;
    int i = b * 256 + t;
    int v = (i < N) ? deg[i] : 0;
    __shared__ int s[256];
    s[t] = v;
    __syncthreads();
    for (int o = 1; o < 256; o <<= 1) {
        int x = (t >= o) ? s[t - o] : 0;
        __syncthreads();
        s[t] += x;
        __syncthreads();
    }
    int incl = s[t];
    int base = bpre[b];
    if (i < N) off[i] = base + incl - v;
    if (i == N - 1) off[N] = base + incl;
}

__global__ void scatter_kernel(const int* __restrict__ src, const int* __restrict__ dst,
                               const int* __restrict__ off, int* __restrict__ cursor,
                               int* __restrict__ csr_src, int E) {
    int e = blockIdx.x * 256 + threadIdx.x;
    if (e < E) {
        int d = dst[e];
        int pos = atomicAdd(&cursor[d], 1);
        csr_src[off[d] + pos] = src[e];
    }
}

// ------------- layer0 aggregation: one block per dst node -----------------------
__global__ __launch_bounds__(256) void agg0_kernel(const float* __restrict__ feat,
                                                   const float* __restrict__ el,
                                                   const float* __restrict__ er,
                                                   const unsigned* __restrict__ gmax,
                                                   const int* __restrict__ off,
                                                   const int* __restrict__ csr_src,
                                                   float* __restrict__ hout) {
    __shared__ int sSrc[256];
    __shared__ float sEx[256 * 4];
    int n = blockIdx.x, tid = threadIdx.x;
    int base = off[n], deg = off[n + 1] - base;
    float C[4], ern[4];
#pragma unroll
    for (int h2 = 0; h2 < 4; ++h2) {
        C[h2] = leaky(dec(gmax[h2]) + dec(gmax[4 + h2]));
        ern[h2] = er[n * 4 + h2];
    }
    int h = tid >> 6;
    float acc = 0.f, den = 0.f;
    for (int j0 = 0; j0 < deg; j0 += 256) {
        int cnt = min(256, deg - j0);
        if (tid < cnt) {
            int s = csr_src[base + j0 + tid];
            sSrc[tid] = s;
            float4 e4 = *(const float4*)&el[(size_t)s * 4];
            sEx[tid * 4 + 0] = expf(leaky(e4.x + ern[0]) - C[0]);
            sEx[tid * 4 + 1] = expf(leaky(e4.y + ern[1]) - C[1]);
            sEx[tid * 4 + 2] = expf(leaky(e4.z + ern[2]) - C[2]);
            sEx[tid * 4 + 3] = expf(leaky(e4.w + ern[3]) - C[3]);
        }
        __syncthreads();
        int j = 0;
        for (; j + 4 <= cnt; j += 4) {
            float w0 = sEx[(j + 0) * 4 + h], w1 = sEx[(j + 1) * 4 + h];
            float w2 = sEx[(j + 2) * 4 + h], w3 = sEx[(j + 3) * 4 + h];
            int s0 = sSrc[j + 0], s1 = sSrc[j + 1], s2 = sSrc[j + 2], s3 = sSrc[j + 3];
            float f0 = feat[(size_t)s0 * 256 + tid];
            float f1 = feat[(size_t)s1 * 256 + tid];
            float f2 = feat[(size_t)s2 * 256 + tid];
            float f3 = feat[(size_t)s3 * 256 + tid];
            acc += w0 * f0; acc += w1 * f1; acc += w2 * f2; acc += w3 * f3;
            den += w0 + w1 + w2 + w3;
        }
        for (; j < cnt; ++j) {
            float w = sEx[j * 4 + h];
            acc += w * feat[(size_t)sSrc[j] * 256 + tid];
            den += w;
        }
        __syncthreads();
    }
    float o = acc / den;
    hout[(size_t)n * 256 + tid] = o > 0.f ? o : expm1f(o);  // ELU
}

// ------------- layer1 aggregation + residual, writes d_out ----------------------
__global__ __launch_bounds__(256) void agg1_kernel(const float* __restrict__ fcat,
                                                   const float* __restrict__ el,
                                                   const float* __restrict__ er,
                                                   const unsigned* __restrict__ gmax,
                                                   const int* __restrict__ off,
                                                   const int* __restrict__ csr_src,
                                                   float* __restrict__ out) {
    __shared__ int sSrc[256];
    __shared__ float sEx[256];
    __shared__ float sAcc[256];
    __shared__ float sDen[8];
    int n = blockIdx.x, tid = threadIdx.x;
    int base = off[n], deg = off[n + 1] - base;
    float C = leaky(dec(gmax[8]) + dec(gmax[9]));
    float ern = er[n];
    int d = tid & 31, g = tid >> 5;
    float acc = 0.f, den = 0.f;
    for (int j0 = 0; j0 < deg; j0 += 256) {
        int cnt = min(256, deg - j0);
        if (tid < cnt) {
            int s = csr_src[base + j0 + tid];
            sSrc[tid] = s;
            sEx[tid] = expf(leaky(el[s] + ern) - C);
        }
        __syncthreads();
        for (int j = g; j < cnt; j += 8) {
            float w = sEx[j];
            acc += w * fcat[(size_t)sSrc[j] * 64 + d];
            den += w;
        }
        __syncthreads();
    }
    sAcc[tid] = acc;
    if (d == 0) sDen[g] = den;
    __syncthreads();
    if (g == 0) {  // tid < 32
        float tot = 0.f, dt = 0.f;
#pragma unroll
        for (int gg = 0; gg < 8; ++gg) {
            tot += sAcc[gg * 32 + d];
            dt += sDen[gg];
        }
        out[(size_t)n * 32 + d] = tot / dt + fcat[(size_t)n * 64 + 32 + d];
    }
}

// ------------- fuse W1|Wres into one [256,64] B matrix ---------------------------
__global__ void fuseb_kernel(const float* __restrict__ W1, const float* __restrict__ Wres,
                             float* __restrict__ Bcat) {
    int i = blockIdx.x * 256 + threadIdx.x;  // 256*64 = 16384
    int r = i >> 6, c = i & 63;
    Bcat[i] = (c < 32) ? W1[r * 32 + c] : Wres[r * 32 + (c - 32)];
}

extern "C" void kernel_launch(void* const* d_in, const int* in_sizes, int n_in,
                              void* d_out, int out_size, void* d_ws, size_t ws_size,
                              hipStream_t stream) {
    const float* x    = (const float*)d_in[0];
    const int*   src  = (const int*)d_in[1];
    const int*   dst  = (const int*)d_in[2];
    const float* W0   = (const float*)d_in[3];
    const float* al0  = (const float*)d_in[4];
    const float* ar0  = (const float*)d_in[5];
    const float* W1   = (const float*)d_in[6];
    const float* al1  = (const float*)d_in[7];
    const float* ar1  = (const float*)d_in[8];
    const float* Wres = (const float*)d_in[9];
    float* out = (float*)d_out;

    const int N = in_sizes[0] / 256;  // 50000
    const int E = in_sizes[1];        // 850000

    // workspace layout
    float* feat0 = (float*)d_ws;                 // N*256
    float* hbuf  = feat0 + (size_t)N * 256;      // N*256
    float* fcat  = hbuf + (size_t)N * 256;       // N*64  (feat1 | hres)
    float* el0   = fcat + (size_t)N * 64;        // N*4
    float* er0   = el0 + (size_t)N * 4;          // N*4
    float* el1   = er0 + (size_t)N * 4;          // N
    float* er1   = el1 + N;                      // N
    float* Bcat  = er1 + N;                      // 256*64
    int*   deg   = (int*)(Bcat + 256 * 64);      // N
    int*   cursor = deg + N;                     // N
    unsigned* gmax = (unsigned*)(cursor + N);    // 16
    int*   offs  = (int*)(gmax + 16);            // N+1
    int*   bsum  = offs + N + 1;                 // 256
    int*   bpre  = bsum + 256;                   // 256
    int*   csr_src = bpre + 256;                 // E

    const int nb = (N + 255) / 256;
    const int eb = (E + 255) / 256;
    const int mb = (N + 63) / 64;

    // zero: deg, cursor, gmax (contiguous)
    hipMemsetAsync(deg, 0, (size_t)(2 * N + 16) * sizeof(int), stream);

    // CSR build
    count_kernel<<<eb, 256, 0, stream>>>(dst, deg, E);
    scanA<<<nb, 256, 0, stream>>>(deg, bsum, N);
    scanB<<<1, 256, 0, stream>>>(bsum, bpre, nb);
    scanC<<<nb, 256, 0, stream>>>(deg, bpre, offs, N);
    scatter_kernel<<<eb, 256, 0, stream>>>(src, dst, offs, cursor, csr_src, E);

    // layer 0
    gemm_tile<<<dim3(mb, 4), 256, 0, stream>>>(x, W0, feat0, N, 256, 256);
    elr0_kernel<<<N, 256, 0, stream>>>(feat0, al0, ar0, el0, er0, gmax);
    agg0_kernel<<<N, 256, 0, stream>>>(feat0, el0, er0, gmax, offs, csr_src, hbuf);

    // layer 1
    fuseb_kernel<<<64, 256, 0, stream>>>(W1, Wres, Bcat);
    gemm_tile<<<dim3(mb, 1), 256, 0, stream>>>(hbuf, Bcat, fcat, N, 64, 256);
    elr1_kernel<<<N, 64, 0, stream>>>(fcat, al1, ar1, el1, er1, gmax);
    agg1_kernel<<<N, 256, 0, stream>>>(fcat, el1, er1, gmax, offs, csr_src, out);
}

// Round 2
// 581.044 us; speedup vs baseline: 10.5293x; 10.5293x over previous
//
#include <hip/hip_runtime.h>
#include <math.h>

#define NEG_SLOPE 0.2f

__device__ __forceinline__ float leaky(float x) { return x > 0.f ? x : NEG_SLOPE * x; }
// monotonic float->uint encoding for atomicMax on floats
__device__ __forceinline__ unsigned enc(float f) {
    unsigned u = __float_as_uint(f);
    return (u & 0x80000000u) ? ~u : (u | 0x80000000u);
}
__device__ __forceinline__ float dec(unsigned e) {
    return (e & 0x80000000u) ? __uint_as_float(e ^ 0x80000000u) : __uint_as_float(~e);
}

// ---------------- GEMM: C[M,Nc] = A[M,K] @ B[K,Nc]; Nc %64==0, K %32==0 -------------
__global__ __launch_bounds__(256) void gemm_tile(const float* __restrict__ A,
                                                 const float* __restrict__ B,
                                                 float* __restrict__ C,
                                                 int M, int Nc, int K) {
    __shared__ float As[32][64];  // [k][m]
    __shared__ float Bs[32][64];  // [k][n]
    const int tid = threadIdx.x;
    const int m0 = blockIdx.x * 64;
    const int n0 = blockIdx.y * 64;
    const int tx = tid & 15, ty = tid >> 4;
    float acc[4][4] = {};
    for (int k0 = 0; k0 < K; k0 += 32) {
        {   // A tile 64 rows x 32 cols, store transposed
            int r = tid >> 3, c4 = tid & 7;
#pragma unroll
            for (int l = 0; l < 2; ++l) {
                int row = r + l * 32;
                float4 v = make_float4(0.f, 0.f, 0.f, 0.f);
                if (m0 + row < M) v = *(const float4*)&A[(size_t)(m0 + row) * K + k0 + c4 * 4];
                As[c4 * 4 + 0][row] = v.x;
                As[c4 * 4 + 1][row] = v.y;
                As[c4 * 4 + 2][row] = v.z;
                As[c4 * 4 + 3][row] = v.w;
            }
        }
        {   // B tile 32 rows x 64 cols
            int kr = tid >> 4, c4 = tid & 15;
#pragma unroll
            for (int l = 0; l < 2; ++l) {
                int row = kr + l * 16;
                float4 v = *(const float4*)&B[(size_t)(k0 + row) * Nc + n0 + c4 * 4];
                *(float4*)&Bs[row][c4 * 4] = v;
            }
        }
        __syncthreads();
#pragma unroll
        for (int k = 0; k < 32; ++k) {
            float a0 = As[k][ty * 4 + 0], a1 = As[k][ty * 4 + 1];
            float a2 = As[k][ty * 4 + 2], a3 = As[k][ty * 4 + 3];
            float4 b = *(const float4*)&Bs[k][tx * 4];
            acc[0][0] += a0 * b.x; acc[0][1] += a0 * b.y; acc[0][2] += a0 * b.z; acc[0][3] += a0 * b.w;
            acc[1][0] += a1 * b.x; acc[1][1] += a1 * b.y; acc[1][2] += a1 * b.z; acc[1][3] += a1 * b.w;
            acc[2][0] += a2 * b.x; acc[2][1] += a2 * b.y; acc[2][2] += a2 * b.z; acc[2][3] += a2 * b.w;
            acc[3][0] += a3 * b.x; acc[3][1] += a3 * b.y; acc[3][2] += a3 * b.z; acc[3][3] += a3 * b.w;
        }
        __syncthreads();
    }
#pragma unroll
    for (int i = 0; i < 4; ++i) {
        int row = m0 + ty * 4 + i;
        if (row < M) {
            float4 v = make_float4(acc[i][0], acc[i][1], acc[i][2], acc[i][3]);
            *(float4*)&C[(size_t)row * Nc + n0 + tx * 4] = v;
        }
    }
}

// ------------- layer0 el/er: [N,4] each, plus global max (encoded) -------------
// Grid-stride, ONE atomicMax per wave at the end (atomic contention fix).
__global__ __launch_bounds__(256) void elr0_kernel(const float* __restrict__ feat,
                                                   const float* __restrict__ al,
                                                   const float* __restrict__ ar,
                                                   float* __restrict__ el, float* __restrict__ er,
                                                   unsigned* __restrict__ gmax, int N) {
    int tid = threadIdx.x;
    int lane = tid & 63, h = tid >> 6;  // wave == head
    float a = al[tid], r = ar[tid];
    float mpe = -1e30f, mpr = -1e30f;
    for (int n = blockIdx.x; n < N; n += gridDim.x) {
        float v = feat[(size_t)n * 256 + tid];
        float pe = v * a;
        float pr = v * r;
#pragma unroll
        for (int o = 32; o > 0; o >>= 1) {
            pe += __shfl_xor(pe, o);
            pr += __shfl_xor(pr, o);
        }
        if (lane == 0) {
            el[n * 4 + h] = pe;
            er[n * 4 + h] = pr;
            mpe = fmaxf(mpe, pe);
            mpr = fmaxf(mpr, pr);
        }
    }
    if (lane == 0) {
        atomicMax(&gmax[h], enc(mpe));
        atomicMax(&gmax[4 + h], enc(mpr));
    }
}

// ------------- layer1 el/er: [N] each; one node per wave, grid-stride ------------
__global__ __launch_bounds__(256) void elr1_kernel(const float* __restrict__ fcat,
                                                   const float* __restrict__ al,
                                                   const float* __restrict__ ar,
                                                   float* __restrict__ el, float* __restrict__ er,
                                                   unsigned* __restrict__ gmax, int N) {
    int tid = threadIdx.x;
    int lane = tid & 63, w = tid >> 6;
    int gw = blockIdx.x * 4 + w;
    int stride = gridDim.x * 4;
    float a = (lane < 32) ? al[lane] : 0.f;
    float r = (lane < 32) ? ar[lane] : 0.f;
    float mpe = -1e30f, mpr = -1e30f;
    for (int n = gw; n < N; n += stride) {
        float v = (lane < 32) ? fcat[(size_t)n * 64 + lane] : 0.f;
        float pe = v * a, pr = v * r;
#pragma unroll
        for (int o = 16; o > 0; o >>= 1) {
            pe += __shfl_xor(pe, o);
            pr += __shfl_xor(pr, o);
        }
        if (lane == 0) {
            el[n] = pe;
            er[n] = pr;
            mpe = fmaxf(mpe, pe);
            mpr = fmaxf(mpr, pr);
        }
    }
    if (lane == 0) {
        atomicMax(&gmax[8], enc(mpe));
        atomicMax(&gmax[9], enc(mpr));
    }
}

// ------------- CSR build ---------------------------------------------------------
__global__ void count_kernel(const int* __restrict__ dst, int* __restrict__ deg, int E) {
    int e = blockIdx.x * 256 + threadIdx.x;
    if (e < E) atomicAdd(&deg[dst[e]], 1);
}

__global__ __launch_bounds__(256) void scanA(const int* __restrict__ deg, int* __restrict__ bsum, int N) {
    int i = blockIdx.x * 256 + threadIdx.x;
    int v = (i < N) ? deg[i] : 0;
#pragma unroll
    for (int o = 32; o > 0; o >>= 1) v += __shfl_xor(v, o);
    __shared__ int s[4];
    if ((threadIdx.x & 63) == 0) s[threadIdx.x >> 6] = v;
    __syncthreads();
    if (threadIdx.x == 0) bsum[blockIdx.x] = s[0] + s[1] + s[2] + s[3];
}

__global__ __launch_bounds__(256) void scanB(const int* __restrict__ bsum, int* __restrict__ bpre, int nb) {
    __shared__ int s[256];
    int t = threadIdx.x;
    int v = (t < nb) ? bsum[t] : 0;
    s[t] = v;
    __syncthreads();
    for (int o = 1; o < 256; o <<= 1) {
        int x = (t >= o) ? s[t - o] : 0;
        __syncthreads();
        s[t] += x;
        __syncthreads();
    }
    if (t < nb) bpre[t] = s[t] - v;  // exclusive
}

__global__ __launch_bounds__(256) void scanC(const int* __restrict__ deg, const int* __restrict__ bpre,
                                             int* __restrict__ off, int N) {
    int b = blockIdx.x, t = threadIdx.x;
    int i = b * 256 + t;
    int v = (i < N) ? deg[i] : 0;
    __shared__ int s[256];
    s[t] = v;
    __syncthreads();
    for (int o = 1; o < 256; o <<= 1) {
        int x = (t >= o) ? s[t - o] : 0;
        __syncthreads();
        s[t] += x;
        __syncthreads();
    }
    int incl = s[t];
    int base = bpre[b];
    if (i < N) off[i] = base + incl - v;
    if (i == N - 1) off[N] = base + incl;
}

__global__ void scatter_kernel(const int* __restrict__ src, const int* __restrict__ dst,
                               const int* __restrict__ off, int* __restrict__ cursor,
                               int* __restrict__ csr_src, int E) {
    int e = blockIdx.x * 256 + threadIdx.x;
    if (e < E) {
        int d = dst[e];
        int pos = atomicAdd(&cursor[d], 1);
        csr_src[off[d] + pos] = src[e];
    }
}

// ------------- layer0 aggregation: one block per dst node -----------------------
__global__ __launch_bounds__(256) void agg0_kernel(const float* __restrict__ feat,
                                                   const float* __restrict__ el,
                                                   const float* __restrict__ er,
                                                   const unsigned* __restrict__ gmax,
                                                   const int* __restrict__ off,
                                                   const int* __restrict__ csr_src,
                                                   float* __restrict__ hout) {
    __shared__ int sSrc[256];
    __shared__ float sEx[256 * 4];
    int n = blockIdx.x, tid = threadIdx.x;
    int base = off[n], deg = off[n + 1] - base;
    float C[4], ern[4];
#pragma unroll
    for (int h2 = 0; h2 < 4; ++h2) {
        C[h2] = leaky(dec(gmax[h2]) + dec(gmax[4 + h2]));
        ern[h2] = er[n * 4 + h2];
    }
    int h = tid >> 6;
    float acc = 0.f, den = 0.f;
    for (int j0 = 0; j0 < deg; j0 += 256) {
        int cnt = min(256, deg - j0);
        if (tid < cnt) {
            int s = csr_src[base + j0 + tid];
            sSrc[tid] = s;
            float4 e4 = *(const float4*)&el[(size_t)s * 4];
            sEx[tid * 4 + 0] = expf(leaky(e4.x + ern[0]) - C[0]);
            sEx[tid * 4 + 1] = expf(leaky(e4.y + ern[1]) - C[1]);
            sEx[tid * 4 + 2] = expf(leaky(e4.z + ern[2]) - C[2]);
            sEx[tid * 4 + 3] = expf(leaky(e4.w + ern[3]) - C[3]);
        }
        __syncthreads();
        int j = 0;
        for (; j + 4 <= cnt; j += 4) {
            float w0 = sEx[(j + 0) * 4 + h], w1 = sEx[(j + 1) * 4 + h];
            float w2 = sEx[(j + 2) * 4 + h], w3 = sEx[(j + 3) * 4 + h];
            int s0 = sSrc[j + 0], s1 = sSrc[j + 1], s2 = sSrc[j + 2], s3 = sSrc[j + 3];
            float f0 = feat[(size_t)s0 * 256 + tid];
            float f1 = feat[(size_t)s1 * 256 + tid];
            float f2 = feat[(size_t)s2 * 256 + tid];
            float f3 = feat[(size_t)s3 * 256 + tid];
            acc += w0 * f0; acc += w1 * f1; acc += w2 * f2; acc += w3 * f3;
            den += w0 + w1 + w2 + w3;
        }
        for (; j < cnt; ++j) {
            float w = sEx[j * 4 + h];
            acc += w * feat[(size_t)sSrc[j] * 256 + tid];
            den += w;
        }
        __syncthreads();
    }
    float o = acc / den;
    hout[(size_t)n * 256 + tid] = o > 0.f ? o : expm1f(o);  // ELU
}

// ------------- layer1 aggregation + residual, writes d_out ----------------------
__global__ __launch_bounds__(256) void agg1_kernel(const float* __restrict__ fcat,
                                                   const float* __restrict__ el,
                                                   const float* __restrict__ er,
                                                   const unsigned* __restrict__ gmax,
                                                   const int* __restrict__ off,
                                                   const int* __restrict__ csr_src,
                                                   float* __restrict__ out) {
    __shared__ int sSrc[256];
    __shared__ float sEx[256];
    __shared__ float sAcc[256];
    __shared__ float sDen[8];
    int n = blockIdx.x, tid = threadIdx.x;
    int base = off[n], deg = off[n + 1] - base;
    float C = leaky(dec(gmax[8]) + dec(gmax[9]));
    float ern = er[n];
    int d = tid & 31, g = tid >> 5;
    float acc = 0.f, den = 0.f;
    for (int j0 = 0; j0 < deg; j0 += 256) {
        int cnt = min(256, deg - j0);
        if (tid < cnt) {
            int s = csr_src[base + j0 + tid];
            sSrc[tid] = s;
            sEx[tid] = expf(leaky(el[s] + ern) - C);
        }
        __syncthreads();
        for (int j = g; j < cnt; j += 8) {
            float w = sEx[j];
            acc += w * fcat[(size_t)sSrc[j] * 64 + d];
            den += w;
        }
        __syncthreads();
    }
    sAcc[tid] = acc;
    if (d == 0) sDen[g] = den;
    __syncthreads();
    if (g == 0) {  // tid < 32
        float tot = 0.f, dt = 0.f;
#pragma unroll
        for (int gg = 0; gg < 8; ++gg) {
            tot += sAcc[gg * 32 + d];
            dt += sDen[gg];
        }
        out[(size_t)n * 32 + d] = tot / dt + fcat[(size_t)n * 64 + 32 + d];
    }
}

// ------------- fuse W1|Wres into one [256,64] B matrix ---------------------------
__global__ void fuseb_kernel(const float* __restrict__ W1, const float* __restrict__ Wres,
                             float* __restrict__ Bcat) {
    int i = blockIdx.x * 256 + threadIdx.x;  // 256*64 = 16384
    int r = i >> 6, c = i & 63;
    Bcat[i] = (c < 32) ? W1[r * 32 + c] : Wres[r * 32 + (c - 32)];
}

extern "C" void kernel_launch(void* const* d_in, const int* in_sizes, int n_in,
                              void* d_out, int out_size, void* d_ws, size_t ws_size,
                              hipStream_t stream) {
    const float* x    = (const float*)d_in[0];
    const int*   src  = (const int*)d_in[1];
    const int*   dst  = (const int*)d_in[2];
    const float* W0   = (const float*)d_in[3];
    const float* al0  = (const float*)d_in[4];
    const float* ar0  = (const float*)d_in[5];
    const float* W1   = (const float*)d_in[6];
    const float* al1  = (const float*)d_in[7];
    const float* ar1  = (const float*)d_in[8];
    const float* Wres = (const float*)d_in[9];
    float* out = (float*)d_out;

    const int N = in_sizes[0] / 256;  // 50000
    const int E = in_sizes[1];        // 850000

    // workspace layout
    float* feat0 = (float*)d_ws;                 // N*256
    float* hbuf  = feat0 + (size_t)N * 256;      // N*256
    float* fcat  = hbuf + (size_t)N * 256;       // N*64  (feat1 | hres)
    float* el0   = fcat + (size_t)N * 64;        // N*4
    float* er0   = el0 + (size_t)N * 4;          // N*4
    float* el1   = er0 + (size_t)N * 4;          // N
    float* er1   = el1 + N;                      // N
    float* Bcat  = er1 + N;                      // 256*64
    int*   deg   = (int*)(Bcat + 256 * 64);      // N
    int*   cursor = deg + N;                     // N
    unsigned* gmax = (unsigned*)(cursor + N);    // 16
    int*   offs  = (int*)(gmax + 16);            // N+1
    int*   bsum  = offs + N + 1;                 // 256
    int*   bpre  = bsum + 256;                   // 256
    int*   csr_src = bpre + 256;                 // E

    const int nb = (N + 255) / 256;
    const int eb = (E + 255) / 256;
    const int mb = (N + 63) / 64;

    // zero: deg, cursor, gmax (contiguous)
    hipMemsetAsync(deg, 0, (size_t)(2 * N + 16) * sizeof(int), stream);

    // CSR build
    count_kernel<<<eb, 256, 0, stream>>>(dst, deg, E);
    scanA<<<nb, 256, 0, stream>>>(deg, bsum, N);
    scanB<<<1, 256, 0, stream>>>(bsum, bpre, nb);
    scanC<<<nb, 256, 0, stream>>>(deg, bpre, offs, N);
    scatter_kernel<<<eb, 256, 0, stream>>>(src, dst, offs, cursor, csr_src, E);

    // layer 0
    gemm_tile<<<dim3(mb, 4), 256, 0, stream>>>(x, W0, feat0, N, 256, 256);
    elr0_kernel<<<512, 256, 0, stream>>>(feat0, al0, ar0, el0, er0, gmax, N);
    agg0_kernel<<<N, 256, 0, stream>>>(feat0, el0, er0, gmax, offs, csr_src, hbuf);

    // layer 1
    fuseb_kernel<<<64, 256, 0, stream>>>(W1, Wres, Bcat);
    gemm_tile<<<dim3(mb, 1), 256, 0, stream>>>(hbuf, Bcat, fcat, N, 64, 256);
    elr1_kernel<<<512, 256, 0, stream>>>(fcat, al1, ar1, el1, er1, gmax, N);
    agg1_kernel<<<N, 256, 0, stream>>>(fcat, el1, er1, gmax, offs, csr_src, out);
}

// Round 3
// 413.101 us; speedup vs baseline: 14.8099x; 1.4065x over previous
//
#include <hip/hip_runtime.h>
#include <math.h>

#define NEG_SLOPE 0.2f

typedef __attribute__((ext_vector_type(8))) short short8;
typedef __attribute__((ext_vector_type(4))) float f32x4;

__device__ __forceinline__ float leaky(float x) { return x > 0.f ? x : NEG_SLOPE * x; }
// monotonic float->uint encoding for atomicMax on floats
__device__ __forceinline__ unsigned enc(float f) {
    unsigned u = __float_as_uint(f);
    return (u & 0x80000000u) ? ~u : (u | 0x80000000u);
}
__device__ __forceinline__ float dec(unsigned e) {
    return (e & 0x80000000u) ? __uint_as_float(e ^ 0x80000000u) : __uint_as_float(~e);
}
// fp32 -> bf16 (RNE) as ushort bits
__device__ __forceinline__ unsigned bf16u(float f) {
    unsigned u = __float_as_uint(f);
    return (u + 0x7fffu + ((u >> 16) & 1u)) >> 16;
}
__device__ __forceinline__ float blo(unsigned u) { return __uint_as_float(u << 16); }
__device__ __forceinline__ float bhi(unsigned u) { return __uint_as_float(u & 0xffff0000u); }

// ---------------- fp32->bf16 convert: 4 floats/thread ---------------------------
__global__ __launch_bounds__(256) void cvt_bf16(const float* __restrict__ in,
                                                unsigned short* __restrict__ outb, int total4) {
    int i = blockIdx.x * 256 + threadIdx.x;
    if (i < total4) {
        float4 v = ((const float4*)in)[i];
        uint2 o;
        o.x = bf16u(v.x) | (bf16u(v.y) << 16);
        o.y = bf16u(v.z) | (bf16u(v.w) << 16);
        ((uint2*)outb)[i] = o;
    }
}

// ---------------- W0 [K=256][N=256] -> W0T bf16 [n][k] ---------------------------
__global__ __launch_bounds__(256) void cvt_w0t(const float* __restrict__ W0,
                                               unsigned short* __restrict__ W0T) {
    int n = blockIdx.x, k = threadIdx.x;
    W0T[n * 256 + k] = (unsigned short)bf16u(W0[k * 256 + n]);
}

// ---------------- bf16 MFMA GEMM: C[M,Nc] = A[M,K] @ Bt[Nc,K]^T ------------------
// A bf16 [M,K] row-major; Bt bf16 [Nc,K] row-major (pre-transposed B).
// grid (ceil(M/64), Nc/64), block 256 (4 waves); wave computes 32x32.
__global__ __launch_bounds__(256) void gemm_bf16(const unsigned short* __restrict__ A,
                                                 const unsigned short* __restrict__ Bt,
                                                 unsigned short* __restrict__ Cb,
                                                 int M, int Nc, int K) {
    __shared__ unsigned short As[64 * 40];  // [m][k], stride 40 (80B) breaks bank conflicts
    __shared__ unsigned short Bs[64 * 40];  // [n][k]
    int tid = threadIdx.x, lane = tid & 63, wv = tid >> 6;
    int m0 = blockIdx.x * 64, n0 = blockIdx.y * 64;
    int wm = (wv >> 1) * 32, wn = (wv & 1) * 32;
    f32x4 acc[2][2] = {};
    int srow = tid >> 2, scol = (tid & 3) * 8;  // 8 ushorts = 16B per thread
    bool avalid = (m0 + srow) < M;
    const unsigned short* Ap = A + (size_t)min(m0 + srow, M - 1) * K + scol;
    const unsigned short* Bp = Bt + (size_t)(n0 + srow) * K + scol;

    for (int k0 = 0; k0 < K; k0 += 32) {
        float4 av = avalid ? *(const float4*)(Ap + k0) : make_float4(0.f, 0.f, 0.f, 0.f);
        float4 bv = *(const float4*)(Bp + k0);
        *(float4*)&As[srow * 40 + scol] = av;
        *(float4*)&Bs[srow * 40 + scol] = bv;
        __syncthreads();
        short8 af[2], bf[2];
#pragma unroll
        for (int i = 0; i < 2; ++i) {
            af[i] = *(const short8*)&As[(wm + i * 16 + (lane & 15)) * 40 + (lane >> 4) * 8];
            bf[i] = *(const short8*)&Bs[(wn + i * 16 + (lane & 15)) * 40 + (lane >> 4) * 8];
        }
#pragma unroll
        for (int i = 0; i < 2; ++i)
#pragma unroll
            for (int j = 0; j < 2; ++j)
                acc[i][j] = __builtin_amdgcn_mfma_f32_16x16x32_bf16(af[i], bf[j], acc[i][j], 0, 0, 0);
        __syncthreads();
    }
    // D: row=(lane>>4)*4+r, col=lane&15 (per 16x16 fragment)
#pragma unroll
    for (int i = 0; i < 2; ++i) {
        int row0 = m0 + wm + i * 16 + (lane >> 4) * 4;
#pragma unroll
        for (int j = 0; j < 2; ++j) {
            int col = n0 + wn + j * 16 + (lane & 15);
#pragma unroll
            for (int r = 0; r < 4; ++r) {
                int row = row0 + r;
                if (row < M) Cb[(size_t)row * Nc + col] = (unsigned short)bf16u(acc[i][j][r]);
            }
        }
    }
}

// ---------------- fp32 GEMM (layer 1, keeps residual path precise) ---------------
__global__ __launch_bounds__(256) void gemm_tile(const float* __restrict__ A,
                                                 const float* __restrict__ B,
                                                 float* __restrict__ C,
                                                 int M, int Nc, int K) {
    __shared__ float As[32][64];
    __shared__ float Bs[32][64];
    const int tid = threadIdx.x;
    const int m0 = blockIdx.x * 64;
    const int n0 = blockIdx.y * 64;
    const int tx = tid & 15, ty = tid >> 4;
    float acc[4][4] = {};
    for (int k0 = 0; k0 < K; k0 += 32) {
        {
            int r = tid >> 3, c4 = tid & 7;
#pragma unroll
            for (int l = 0; l < 2; ++l) {
                int row = r + l * 32;
                float4 v = make_float4(0.f, 0.f, 0.f, 0.f);
                if (m0 + row < M) v = *(const float4*)&A[(size_t)(m0 + row) * K + k0 + c4 * 4];
                As[c4 * 4 + 0][row] = v.x;
                As[c4 * 4 + 1][row] = v.y;
                As[c4 * 4 + 2][row] = v.z;
                As[c4 * 4 + 3][row] = v.w;
            }
        }
        {
            int kr = tid >> 4, c4 = tid & 15;
#pragma unroll
            for (int l = 0; l < 2; ++l) {
                int row = kr + l * 16;
                float4 v = *(const float4*)&B[(size_t)(k0 + row) * Nc + n0 + c4 * 4];
                *(float4*)&Bs[row][c4 * 4] = v;
            }
        }
        __syncthreads();
#pragma unroll
        for (int k = 0; k < 32; ++k) {
            float a0 = As[k][ty * 4 + 0], a1 = As[k][ty * 4 + 1];
            float a2 = As[k][ty * 4 + 2], a3 = As[k][ty * 4 + 3];
            float4 b = *(const float4*)&Bs[k][tx * 4];
            acc[0][0] += a0 * b.x; acc[0][1] += a0 * b.y; acc[0][2] += a0 * b.z; acc[0][3] += a0 * b.w;
            acc[1][0] += a1 * b.x; acc[1][1] += a1 * b.y; acc[1][2] += a1 * b.z; acc[1][3] += a1 * b.w;
            acc[2][0] += a2 * b.x; acc[2][1] += a2 * b.y; acc[2][2] += a2 * b.z; acc[2][3] += a2 * b.w;
            acc[3][0] += a3 * b.x; acc[3][1] += a3 * b.y; acc[3][2] += a3 * b.z; acc[3][3] += a3 * b.w;
        }
        __syncthreads();
    }
#pragma unroll
    for (int i = 0; i < 4; ++i) {
        int row = m0 + ty * 4 + i;
        if (row < M) {
            float4 v = make_float4(acc[i][0], acc[i][1], acc[i][2], acc[i][3]);
            *(float4*)&C[(size_t)row * Nc + n0 + tx * 4] = v;
        }
    }
}

// ------------- layer0 el/er from bf16 feat; grid-stride; 1 atomic per writer ----
__global__ __launch_bounds__(128) void elr0_kernel(const unsigned short* __restrict__ featb,
                                                   const float* __restrict__ al,
                                                   const float* __restrict__ ar,
                                                   float* __restrict__ el, float* __restrict__ er,
                                                   unsigned* __restrict__ gmax, int N) {
    int tid = threadIdx.x;           // 128 threads; dims 2*tid, 2*tid+1
    int h = tid >> 5;                // head (dims within one head per 32-lane group)
    float a0 = al[tid * 2], a1 = al[tid * 2 + 1];
    float r0 = ar[tid * 2], r1 = ar[tid * 2 + 1];
    float mpe = -1e30f, mpr = -1e30f;
    bool writer = (tid & 31) == 0;
    for (int n = blockIdx.x; n < N; n += gridDim.x) {
        unsigned u = *(const unsigned*)&featb[(size_t)n * 256 + tid * 2];
        float f0 = blo(u), f1 = bhi(u);
        float pe = f0 * a0 + f1 * a1;
        float pr = f0 * r0 + f1 * r1;
#pragma unroll
        for (int o = 16; o > 0; o >>= 1) {
            pe += __shfl_xor(pe, o);
            pr += __shfl_xor(pr, o);
        }
        if (writer) {
            el[n * 4 + h] = pe;
            er[n * 4 + h] = pr;
            mpe = fmaxf(mpe, pe);
            mpr = fmaxf(mpr, pr);
        }
    }
    if (writer) {
        atomicMax(&gmax[h], enc(mpe));
        atomicMax(&gmax[4 + h], enc(mpr));
    }
}

// ------------- layer1 el/er: [N] each; one node per wave, grid-stride ------------
__global__ __launch_bounds__(256) void elr1_kernel(const float* __restrict__ fcat,
                                                   const float* __restrict__ al,
                                                   const float* __restrict__ ar,
                                                   float* __restrict__ el, float* __restrict__ er,
                                                   unsigned* __restrict__ gmax, int N) {
    int tid = threadIdx.x;
    int lane = tid & 63, w = tid >> 6;
    int gw = blockIdx.x * 4 + w;
    int stride = gridDim.x * 4;
    float a = (lane < 32) ? al[lane] : 0.f;
    float r = (lane < 32) ? ar[lane] : 0.f;
    float mpe = -1e30f, mpr = -1e30f;
    for (int n = gw; n < N; n += stride) {
        float v = (lane < 32) ? fcat[(size_t)n * 64 + lane] : 0.f;
        float pe = v * a, pr = v * r;
#pragma unroll
        for (int o = 16; o > 0; o >>= 1) {
            pe += __shfl_xor(pe, o);
            pr += __shfl_xor(pr, o);
        }
        if (lane == 0) {
            el[n] = pe;
            er[n] = pr;
            mpe = fmaxf(mpe, pe);
            mpr = fmaxf(mpr, pr);
        }
    }
    if (lane == 0) {
        atomicMax(&gmax[8], enc(mpe));
        atomicMax(&gmax[9], enc(mpr));
    }
}

// ------------- CSR build ---------------------------------------------------------
__global__ void count_kernel(const int* __restrict__ dst, int* __restrict__ deg, int E) {
    int e = blockIdx.x * 256 + threadIdx.x;
    if (e < E) atomicAdd(&deg[dst[e]], 1);
}

__global__ __launch_bounds__(256) void scanA(const int* __restrict__ deg, int* __restrict__ bsum, int N) {
    int i = blockIdx.x * 256 + threadIdx.x;
    int v = (i < N) ? deg[i] : 0;
#pragma unroll
    for (int o = 32; o > 0; o >>= 1) v += __shfl_xor(v, o);
    __shared__ int s[4];
    if ((threadIdx.x & 63) == 0) s[threadIdx.x >> 6] = v;
    __syncthreads();
    if (threadIdx.x == 0) bsum[blockIdx.x] = s[0] + s[1] + s[2] + s[3];
}

__global__ __launch_bounds__(256) void scanB(const int* __restrict__ bsum, int* __restrict__ bpre, int nb) {
    __shared__ int s[256];
    int t = threadIdx.x;
    int v = (t < nb) ? bsum[t] : 0;
    s[t] = v;
    __syncthreads();
    for (int o = 1; o < 256; o <<= 1) {
        int x = (t >= o) ? s[t - o] : 0;
        __syncthreads();
        s[t] += x;
        __syncthreads();
    }
    if (t < nb) bpre[t] = s[t] - v;  // exclusive
}

__global__ __launch_bounds__(256) void scanC(const int* __restrict__ deg, const int* __restrict__ bpre,
                                             int* __restrict__ off, int N) {
    int b = blockIdx.x, t = threadIdx.x;
    int i = b * 256 + t;
    int v = (i < N) ? deg[i] : 0;
    __shared__ int s[256];
    s[t] = v;
    __syncthreads();
    for (int o = 1; o < 256; o <<= 1) {
        int x = (t >= o) ? s[t - o] : 0;
        __syncthreads();
        s[t] += x;
        __syncthreads();
    }
    int incl = s[t];
    int base = bpre[b];
    if (i < N) off[i] = base + incl - v;
    if (i == N - 1) off[N] = base + incl;
}

__global__ void scatter_kernel(const int* __restrict__ src, const int* __restrict__ dst,
                               const int* __restrict__ off, int* __restrict__ cursor,
                               int* __restrict__ csr_src, int E) {
    int e = blockIdx.x * 256 + threadIdx.x;
    if (e < E) {
        int d = dst[e];
        int pos = atomicAdd(&cursor[d], 1);
        csr_src[off[d] + pos] = src[e];
    }
}

// ------------- layer0 aggregation: ONE WAVE per dst node, bf16 gather ------------
__global__ __launch_bounds__(64) void agg0_kernel(const unsigned short* __restrict__ featb,
                                                  const float* __restrict__ el,
                                                  const float* __restrict__ er,
                                                  const unsigned* __restrict__ gmax,
                                                  const int* __restrict__ off,
                                                  const int* __restrict__ csr_src,
                                                  float* __restrict__ hout) {
    int n = blockIdx.x, lane = threadIdx.x;  // lane handles dims lane*4 .. +3
    int base = off[n], deg = off[n + 1] - base;
    int h = lane >> 4;  // head of this lane's dims
    float Ch = leaky(dec(gmax[h]) + dec(gmax[4 + h]));
    float ern = er[n * 4 + h];
    float a0 = 0.f, a1 = 0.f, a2 = 0.f, a3 = 0.f, den = 0.f;
    for (int j0 = 0; j0 < deg; j0 += 16) {
        int jj = j0 + (lane & 15);
        int sld = csr_src[base + min(jj, deg - 1)];
        float wreg = 0.f;
        if (jj < deg) wreg = expf(leaky(el[sld * 4 + h] + ern) - Ch);
        int cnt = min(16, deg - j0);
        for (int j = 0; j < cnt; ++j) {
            float w = __shfl(wreg, (lane & 48) + j);  // broadcast within 16-lane group (same h)
            int s = __shfl(sld, j);
            uint2 u = *(const uint2*)&featb[(size_t)s * 256 + lane * 4];
            a0 += w * blo(u.x);
            a1 += w * bhi(u.x);
            a2 += w * blo(u.y);
            a3 += w * bhi(u.y);
            den += w;
        }
    }
    float inv = 1.f / den;
    float4 o;
    o.x = a0 * inv; o.y = a1 * inv; o.z = a2 * inv; o.w = a3 * inv;
    o.x = o.x > 0.f ? o.x : expm1f(o.x);
    o.y = o.y > 0.f ? o.y : expm1f(o.y);
    o.z = o.z > 0.f ? o.z : expm1f(o.z);
    o.w = o.w > 0.f ? o.w : expm1f(o.w);
    *(float4*)&hout[(size_t)n * 256 + lane * 4] = o;
}

// ------------- layer1 aggregation + residual: ONE WAVE per node, 2 edges/pass ----
__global__ __launch_bounds__(64) void agg1_kernel(const float* __restrict__ fcat,
                                                  const float* __restrict__ el,
                                                  const float* __restrict__ er,
                                                  const unsigned* __restrict__ gmax,
                                                  const int* __restrict__ off,
                                                  const int* __restrict__ csr_src,
                                                  float* __restrict__ out) {
    int n = blockIdx.x, lane = threadIdx.x;
    int base = off[n], deg = off[n + 1] - base;
    float C = leaky(dec(gmax[8]) + dec(gmax[9]));
    float ern = er[n];
    int d = lane & 31, g = lane >> 5;
    float acc = 0.f, den = 0.f;
    for (int j0 = 0; j0 < deg; j0 += 64) {
        int jj = j0 + lane;
        int sld = csr_src[base + min(jj, deg - 1)];
        float wreg = (jj < deg) ? expf(leaky(el[sld] + ern) - C) : 0.f;
        int cnt = min(64, deg - j0);
        for (int j = g; j < cnt; j += 2) {
            float w = __shfl(wreg, j);
            int s = __shfl(sld, j);
            acc += w * fcat[(size_t)s * 64 + d];
            den += w;
        }
    }
    den += __shfl_xor(den, 32);
    acc += __shfl_xor(acc, 32);
    if (lane < 32)
        out[(size_t)n * 32 + d] = acc / den + fcat[(size_t)n * 64 + 32 + d];
}

// ------------- fuse W1|Wres into one [256,64] fp32 B matrix ----------------------
__global__ void fuseb_kernel(const float* __restrict__ W1, const float* __restrict__ Wres,
                             float* __restrict__ Bcat) {
    int i = blockIdx.x * 256 + threadIdx.x;  // 256*64 = 16384
    int r = i >> 6, c = i & 63;
    Bcat[i] = (c < 32) ? W1[r * 32 + c] : Wres[r * 32 + (c - 32)];
}

extern "C" void kernel_launch(void* const* d_in, const int* in_sizes, int n_in,
                              void* d_out, int out_size, void* d_ws, size_t ws_size,
                              hipStream_t stream) {
    const float* x    = (const float*)d_in[0];
    const int*   src  = (const int*)d_in[1];
    const int*   dst  = (const int*)d_in[2];
    const float* W0   = (const float*)d_in[3];
    const float* al0  = (const float*)d_in[4];
    const float* ar0  = (const float*)d_in[5];
    const float* W1   = (const float*)d_in[6];
    const float* al1  = (const float*)d_in[7];
    const float* ar1  = (const float*)d_in[8];
    const float* Wres = (const float*)d_in[9];
    float* out = (float*)d_out;

    const int N = in_sizes[0] / 256;  // 50000
    const int E = in_sizes[1];        // 850000

    // workspace layout (16B-aligned chunks first)
    float* hbuf  = (float*)d_ws;                      // N*256 fp32
    float* fcat  = hbuf + (size_t)N * 256;            // N*64 fp32 (feat1 | hres)
    float* el0   = fcat + (size_t)N * 64;             // N*4
    float* er0   = el0 + (size_t)N * 4;               // N*4
    float* el1   = er0 + (size_t)N * 4;               // N
    float* er1   = el1 + N;                           // N
    float* Bcat  = er1 + N;                           // 256*64 fp32
    unsigned short* feat0b = (unsigned short*)(Bcat + 256 * 64);  // N*256 bf16
    unsigned short* xb     = feat0b + (size_t)N * 256;            // N*256 bf16
    unsigned short* W0T    = xb + (size_t)N * 256;                // 256*256 bf16
    int*   deg    = (int*)(W0T + 256 * 256);          // N
    int*   cursor = deg + N;                          // N
    unsigned* gmax = (unsigned*)(cursor + N);         // 16
    int*   offs  = (int*)(gmax + 16);                 // N+1
    int*   bsum  = offs + N + 1;                      // 256
    int*   bpre  = bsum + 256;                        // 256
    int*   csr_src = bpre + 256;                      // E

    const int nb = (N + 255) / 256;
    const int eb = (E + 255) / 256;
    const int mb = (N + 63) / 64;

    // zero: deg, cursor, gmax (contiguous)
    hipMemsetAsync(deg, 0, (size_t)(2 * N + 16) * sizeof(int), stream);

    // input conversions
    cvt_bf16<<<(N * 256 / 4 + 255) / 256, 256, 0, stream>>>(x, xb, N * 256 / 4);
    cvt_w0t<<<256, 256, 0, stream>>>(W0, W0T);
    fuseb_kernel<<<64, 256, 0, stream>>>(W1, Wres, Bcat);

    // CSR build
    count_kernel<<<eb, 256, 0, stream>>>(dst, deg, E);
    scanA<<<nb, 256, 0, stream>>>(deg, bsum, N);
    scanB<<<1, 256, 0, stream>>>(bsum, bpre, nb);
    scanC<<<nb, 256, 0, stream>>>(deg, bpre, offs, N);
    scatter_kernel<<<eb, 256, 0, stream>>>(src, dst, offs, cursor, csr_src, E);

    // layer 0: bf16 MFMA GEMM -> bf16 feat0
    gemm_bf16<<<dim3(mb, 4), 256, 0, stream>>>(xb, W0T, feat0b, N, 256, 256);
    elr0_kernel<<<1024, 128, 0, stream>>>(feat0b, al0, ar0, el0, er0, gmax, N);
    agg0_kernel<<<N, 64, 0, stream>>>(feat0b, el0, er0, gmax, offs, csr_src, hbuf);

    // layer 1: fp32 (protects residual-path precision)
    gemm_tile<<<dim3(mb, 1), 256, 0, stream>>>(hbuf, Bcat, fcat, N, 64, 256);
    elr1_kernel<<<512, 256, 0, stream>>>(fcat, al1, ar1, el1, er1, gmax, N);
    agg1_kernel<<<N, 64, 0, stream>>>(fcat, el1, er1, gmax, offs, csr_src, out);
}